// Round 1
// baseline (311.542 us; speedup 1.0000x reference)
//
#include <hip/hip_runtime.h>

#define EPS 1e-10f

// 16 lanes per ray, 4 rays per wave, 16 rays per 256-thread block.
// Lane sl (0..15) owns samples 8*sl .. 8*sl+7 of its ray.
__global__ __launch_bounds__(256) void vr_kernel(
    const float* __restrict__ alpha,   // [R,128]
    const float* __restrict__ rgbs,    // [R,128,3]
    float* __restrict__ out,           // [R,3]
    int R)
{
    const int gtid = blockIdx.x * blockDim.x + threadIdx.x;
    const int ray  = gtid >> 4;
    const int sl   = threadIdx.x & 15;
    if (ray >= R) return;

    // ---- alpha: 2 x float4, fully 16B-per-lane vectorized ----
    const float* a = alpha + (size_t)ray * 128 + 8 * sl;
    const float4 a0 = *(const float4*)(a);
    const float4 a1 = *(const float4*)(a + 4);

    float av[8];
    av[0]=a0.x; av[1]=a0.y; av[2]=a0.z; av[3]=a0.w;
    av[4]=a1.x; av[5]=a1.y; av[6]=a1.z; av[7]=a1.w;

    // local exclusive prefixes p[i] = prod_{k<i} t_k ; p[8] = full local product
    float p[9];
    p[0] = 1.0f;
    #pragma unroll
    for (int i = 0; i < 8; ++i) {
        const float t = 1.0f - av[i] + EPS;
        p[i+1] = p[i] * t;
    }

    // ---- issue rgb loads early so they overlap the scan ----
    const float4* cp = (const float4*)(rgbs + (size_t)ray * 384 + 24 * sl);
    float f[24];
    #pragma unroll
    for (int i = 0; i < 6; ++i) {
        const float4 v = cp[i];
        f[4*i+0]=v.x; f[4*i+1]=v.y; f[4*i+2]=v.z; f[4*i+3]=v.w;
    }

    // ---- inclusive product-scan across the 16-lane segment ----
    float scan = p[8];
    #pragma unroll
    for (int off = 1; off < 16; off <<= 1) {
        const float v = __shfl_up(scan, off, 16);
        if (sl >= off) scan *= v;
    }
    // exclusive prefix: product of all earlier lanes' local products
    float excl = __shfl_up(scan, 1, 16);
    if (sl == 0) excl = 1.0f;

    // weights: w_i = excl * p[i] * alpha_i   (trans is exclusive cumprod, shift=1)
    float w[8];
    #pragma unroll
    for (int i = 0; i < 8; ++i) w[i] = excl * p[i] * av[i];

    float sr = 0.f, sg = 0.f, sb = 0.f;
    #pragma unroll
    for (int i = 0; i < 8; ++i) {
        sr += w[i] * f[3*i+0];
        sg += w[i] * f[3*i+1];
        sb += w[i] * f[3*i+2];
    }

    // ---- reduce across 16-lane segment (4 steps x 3 colors) ----
    #pragma unroll
    for (int off = 8; off > 0; off >>= 1) {
        sr += __shfl_down(sr, off, 16);
        sg += __shfl_down(sg, off, 16);
        sb += __shfl_down(sb, off, 16);
    }

    if (sl == 0) {
        float* o = out + (size_t)ray * 3;
        o[0] = sr;
        o[1] = sg;
        o[2] = sb;
    }
}

extern "C" void kernel_launch(void* const* d_in, const int* in_sizes, int n_in,
                              void* d_out, int out_size, void* d_ws, size_t ws_size,
                              hipStream_t stream) {
    const float* alpha = (const float*)d_in[0];
    const float* rgbs  = (const float*)d_in[1];
    float* out = (float*)d_out;

    const int R = in_sizes[0] / 128;          // 131072
    const int rays_per_block = 256 / 16;      // 16 rays per block
    const int grid = (R + rays_per_block - 1) / rays_per_block;

    vr_kernel<<<grid, 256, 0, stream>>>(alpha, rgbs, out, R);
}

// Round 2
// 311.019 us; speedup vs baseline: 1.0017x; 1.0017x over previous
//
#include <hip/hip_runtime.h>

#define EPS 1e-10f
#define RPB 16          // rays per 256-thread block
#define ARS 132         // LDS ray stride for alpha (128 + 4 pad) -> spreads banks
#define CRS 388         // LDS ray stride for rgb   (384 + 4 pad)

// Stage both inputs through LDS with perfectly dense float4 global loads,
// then compute with 16-lanes-per-ray segmented scan (17 shuffles/wave).
__global__ __launch_bounds__(256) void vr_kernel(
    const float* __restrict__ alpha,   // [R,128]
    const float* __restrict__ rgbs,    // [R,128,3]
    float* __restrict__ out,           // [R,3]
    int R)
{
    __shared__ float la[RPB * ARS];    // 8448 B
    __shared__ float lc[RPB * CRS];    // 24832 B

    const int t = threadIdx.x;
    const long long blockRay = (long long)blockIdx.x * RPB;

    // ---- dense global->LDS staging: every load is 16B/lane, stride 16B ----
    // alpha: 512 float4 per block
    {
        const long long base = blockRay * 32;              // float4 units
        const long long last = (long long)R * 32 - 1;
        #pragma unroll
        for (int j = 0; j < 2; ++j) {
            const int idx = t + 256 * j;                   // 0..511
            long long g = base + idx; if (g > last) g = last;   // tail clamp
            const float4 v = ((const float4*)alpha)[g];
            const int ray = idx >> 5;                      // 32 float4 per ray
            const int off = (idx & 31) << 2;
            *(float4*)(&la[ray * ARS + off]) = v;
        }
    }
    // rgbs: 1536 float4 per block
    {
        const long long base = blockRay * 96;
        const long long last = (long long)R * 96 - 1;
        #pragma unroll
        for (int j = 0; j < 6; ++j) {
            const int idx = t + 256 * j;                   // 0..1535
            long long g = base + idx; if (g > last) g = last;
            const float4 v = ((const float4*)rgbs)[g];
            const int ray = idx / 96;                      // 96 float4 per ray
            const int off = (idx - ray * 96) << 2;
            *(float4*)(&lc[ray * CRS + off]) = v;
        }
    }
    __syncthreads();

    // ---- compute: 16 lanes per ray, lane sl owns samples 8sl..8sl+7 ----
    const int s  = t >> 4;
    const int sl = t & 15;
    const long long ray = blockRay + s;

    const float4 a0 = *(const float4*)(&la[s * ARS + 8 * sl]);
    const float4 a1 = *(const float4*)(&la[s * ARS + 8 * sl + 4]);
    float av[8] = {a0.x, a0.y, a0.z, a0.w, a1.x, a1.y, a1.z, a1.w};

    // local exclusive prefix products
    float p[9];
    p[0] = 1.0f;
    #pragma unroll
    for (int i = 0; i < 8; ++i)
        p[i + 1] = p[i] * (1.0f - av[i] + EPS);

    // rgb from LDS: 6 x b128, banks spread by CRS pad
    float f[24];
    {
        const float* cbase = &lc[s * CRS + 24 * sl];
        #pragma unroll
        for (int i = 0; i < 6; ++i) {
            const float4 v = *(const float4*)(cbase + 4 * i);
            f[4*i+0] = v.x; f[4*i+1] = v.y; f[4*i+2] = v.z; f[4*i+3] = v.w;
        }
    }

    // segmented inclusive product-scan over 16 lanes
    float scan = p[8];
    #pragma unroll
    for (int off = 1; off < 16; off <<= 1) {
        const float v = __shfl_up(scan, off, 16);
        if (sl >= off) scan *= v;
    }
    float excl = __shfl_up(scan, 1, 16);
    if (sl == 0) excl = 1.0f;

    float w[8];
    #pragma unroll
    for (int i = 0; i < 8; ++i) w[i] = excl * p[i] * av[i];

    float sr = 0.f, sg = 0.f, sb = 0.f;
    #pragma unroll
    for (int i = 0; i < 8; ++i) {
        sr += w[i] * f[3*i+0];
        sg += w[i] * f[3*i+1];
        sb += w[i] * f[3*i+2];
    }

    #pragma unroll
    for (int off = 8; off > 0; off >>= 1) {
        sr += __shfl_down(sr, off, 16);
        sg += __shfl_down(sg, off, 16);
        sb += __shfl_down(sb, off, 16);
    }

    if (sl == 0 && ray < R) {
        float* o = out + ray * 3;
        o[0] = sr;
        o[1] = sg;
        o[2] = sb;
    }
}

extern "C" void kernel_launch(void* const* d_in, const int* in_sizes, int n_in,
                              void* d_out, int out_size, void* d_ws, size_t ws_size,
                              hipStream_t stream) {
    const float* alpha = (const float*)d_in[0];
    const float* rgbs  = (const float*)d_in[1];
    float* out = (float*)d_out;

    const int R = in_sizes[0] / 128;              // 131072
    const int grid = (R + RPB - 1) / RPB;         // 8192 blocks

    vr_kernel<<<grid, 256, 0, stream>>>(alpha, rgbs, out, R);
}